// Round 18
// baseline (97.545 us; speedup 1.0000x reference)
//
#include <hip/hip_runtime.h>
#include <hip/hip_bf16.h>

typedef __bf16 bf16x8 __attribute__((ext_vector_type(8)));
typedef float  f32x4  __attribute__((ext_vector_type(4)));
typedef float  f32x16 __attribute__((ext_vector_type(16)));

#define NB 16
#define NC 32
#define NH 32
#define NW 2048
#define NK (NC*NH)   // 1024
#define LOG2E 1.4426950408889634f

static __device__ __forceinline__ unsigned int pk2(float a, float b) {
    union { __bf16 h[2]; unsigned int u; } z;
    z.h[0] = (__bf16)a; z.h[1] = (__bf16)b;
    return z.u;
}

// ---------------------------------------------------------------------------
// Kernel 0: weights -> bf16. wb layout [3][32][1024]; wq scaled by log2e.
// ---------------------------------------------------------------------------
__global__ __launch_bounds__(256) void wprep_kernel(
    const float* __restrict__ wq, const float* __restrict__ wk,
    const float* __restrict__ wv, __bf16* __restrict__ wb)
{
    const int i = blockIdx.x * 256 + threadIdx.x;        // 24576 float4 units
    const float* srcs[3] = { wq, wk, wv };
    float4 v = *(const float4*)(srcs[i >> 13] + (size_t)(i & 8191) * 4);
    const float sc = (i >> 13) == 0 ? LOG2E : 1.0f;
    union { __bf16 h[4]; unsigned long long u; } z;
    z.h[0] = (__bf16)(v.x * sc); z.h[1] = (__bf16)(v.y * sc);
    z.h[2] = (__bf16)(v.z * sc); z.h[3] = (__bf16)(v.w * sc);
    *(unsigned long long*)(wb + (size_t)i * 4) = z.u;
}

// ---------------------------------------------------------------------------
// Kernel 1 (v7): QKV projection = v4 skeleton + T2 XOR-swizzled LDS.
// LDS tile [2][32 w][64 k] bf16 (16 KB), 16B units swizzled by w:
//   elem(w,k) = w*64 + ((k>>3)^(w&7))*8 + (k&7)
// -> staging ds_write_b16s land on 32 distinct banks (2 lanes/bank = free;
//    v4's layout was 8-way conflicted), and A-frag ds_read_b128 stays
//    16B-aligned with only free 2-way row aliasing.
// 64-k steps: 16 barriers (v4 had 32); loads rotated 2 steps ahead in
// statically-named registers; fully unrolled. 6 waves (384 thr): all
// compute, waves 0..3 also stage. Grid = 1024 blocks.
// ---------------------------------------------------------------------------
__global__ __launch_bounds__(384) void proj_kernel(
    const float* __restrict__ x, const __bf16* __restrict__ wb,
    const float* __restrict__ bq, const float* __restrict__ bk,
    const float* __restrict__ bv,
    __bf16* __restrict__ qT, __bf16* __restrict__ kT, __bf16* __restrict__ V)
{
    const int b    = blockIdx.x >> 6;
    const int wt   = blockIdx.x & 63;
    const int nt   = threadIdx.x >> 6;       // wave = output ntile 0..5
    const int lane = threadIdx.x & 63;
    const int g    = lane >> 4;
    const int lr   = lane & 15;
    const int w0   = wt * 32;

    __shared__ __bf16 tile[2][32][64];       // 16 KB, XOR-swizzled units

    const float* xb = x + (size_t)b * NK * NW;
    const int skr = threadIdx.x >> 3;        // 0..31 (stagers)
    const int swq = threadIdx.x & 7;
    const bool stager = (threadIdx.x < 256);
    const float* xs = xb + w0 + swq * 4;

    const __bf16* wrow = wb + (size_t)(nt >> 1) * 32768
                            + (size_t)((nt & 1) * 16 + lr) * NK;

    f32x4 acc0 = {0.f,0.f,0.f,0.f}, acc1 = {0.f,0.f,0.f,0.f};
    f32x4 xA0, xA1, xB0, xB1;                // 2-step rotation, static names

#define PLOAD(D0, D1, S)                                                      \
    { D0 = *(const f32x4*)(xs + (size_t)((S)*64 + skr) * NW);                 \
      D1 = *(const f32x4*)(xs + (size_t)((S)*64 + 32 + skr) * NW); }

#define PWRITE(S0, S1, S)                                                     \
    { __bf16* tb = &tile[(S) & 1][0][0];                                      \
      _Pragma("unroll")                                                       \
      for (int e = 0; e < 4; ++e) {                                           \
          const int w = swq*4 + e;                                            \
          tb[w*64 + (((skr>>3)      ^ (w&7))*8) + (skr&7)] = (__bf16)S0[e];   \
          tb[w*64 + (((4+(skr>>3))  ^ (w&7))*8) + (skr&7)] = (__bf16)S1[e];   \
      } }

#define PCOMP(S)                                                              \
    { _Pragma("unroll")                                                       \
      for (int kc = 0; kc < 2; ++kc) {                                        \
          const int u = ((kc*4 + g) ^ (lr & 7)) * 8;                          \
          const bf16x8 af0 = *(const bf16x8*)&tile[(S)&1][lr][u];             \
          const bf16x8 af1 = *(const bf16x8*)&tile[(S)&1][16 + lr][u];        \
          const bf16x8 Bf  = *(const bf16x8*)(wrow + (S)*64 + kc*32 + g*8);   \
          acc0 = __builtin_amdgcn_mfma_f32_16x16x32_bf16(af0, Bf, acc0,0,0,0);\
          acc1 = __builtin_amdgcn_mfma_f32_16x16x32_bf16(af1, Bf, acc1,0,0,0);\
      } }

    // prologue: x(0) -> buf0 ; x(1) -> B-regs
    if (stager) {
        PLOAD(xA0, xA1, 0);
        PWRITE(xA0, xA1, 0);
        PLOAD(xB0, xB1, 1);
    }
    __syncthreads();

    #pragma unroll
    for (int s = 0; s < 16; ++s) {
        // (a) ds_write x(s+1) into the other buffer (conflict-free)
        if (stager && s < 15) {
            if ((s + 1) & 1) { PWRITE(xB0, xB1, s + 1); }
            else             { PWRITE(xA0, xA1, s + 1); }
        }
        // (b) issue global load x(s+2) into the freed register pair
        if (stager && s < 14) {
            if ((s + 2) & 1) { PLOAD(xB0, xB1, s + 2); }
            else             { PLOAD(xA0, xA1, s + 2); }
        }
        // (c) consume buf[s&1]: 4 swizzled ds_read_b128 + 4 MFMA
        PCOMP(s);
        __syncthreads();
    }
#undef PLOAD
#undef PWRITE
#undef PCOMP

    // ---- epilogue: bias + store this wave's 16 channels x 32 w ----
    const int pid = nt >> 1;                 // 0=q,1=k,2=v
    const int o   = (nt & 1) * 16 + lr;
    const float* biases[3] = { bq, bk, bv };
    float bb = biases[pid][o];
    if (pid == 0) bb *= LOG2E;

    if (pid < 2) {
        __bf16* dst = (pid ? kT : qT) + (size_t)b * NW * NC;
        #pragma unroll
        for (int r = 0; r < 4; ++r) {
            dst[(size_t)(w0 +      g*4 + r) * NC + o] = (__bf16)(acc0[r] + bb);
            dst[(size_t)(w0 + 16 + g*4 + r) * NC + o] = (__bf16)(acc1[r] + bb);
        }
    } else {
        __bf16* dst = V + ((size_t)b * NC + o) * NW + w0;
        union { __bf16 h[4]; unsigned long long u; } z0, z1;
        #pragma unroll
        for (int r = 0; r < 4; ++r) {
            z0.h[r] = (__bf16)(acc0[r] + bb);
            z1.h[r] = (__bf16)(acc1[r] + bb);
        }
        *(unsigned long long*)(dst +      g*4) = z0.u;
        *(unsigned long long*)(dst + 16 + g*4) = z1.u;
    }
}

// ---------------------------------------------------------------------------
// Kernel 2: flash attention (R10/R14, unchanged/verified): fixed-max softmax,
// sigma-permuted K rows (lane-local PV fragments), software-pipelined loop,
// exp2 via __builtin_amdgcn_exp2f, NT out stores.
// ---------------------------------------------------------------------------
__global__ __launch_bounds__(256) void attn_kernel(
    const float* __restrict__ x,
    const __bf16* __restrict__ qT, const __bf16* __restrict__ kT,
    const __bf16* __restrict__ V,
    float* __restrict__ out)
{
    const int b    = blockIdx.x >> 6;
    const int wt   = blockIdx.x & 63;
    const int w0   = wt * 32;
    const int wave = threadIdx.x >> 6;        // KV slice 0..3
    const int lane = threadIdx.x & 63;
    const int wl = lane & 31, hi = lane >> 5;
    const int swl = (wl & 0x13) | ((wl & 4) << 1) | ((wl & 8) >> 1);

    const __bf16* qTb = qT + (size_t)b * NW * NC;
    const __bf16* kTb = kT + (size_t)b * NW * NC;
    const __bf16* Vb  = V  + (size_t)b * NC * NW;

    const __bf16* qrow = qTb + (size_t)(w0 + wl) * NC;
    const bf16x8 qf0 = *(const bf16x8*)(qrow + hi*8);
    const bf16x8 qf1 = *(const bf16x8*)(qrow + 16 + hi*8);

    f32x16 acc, z16;
    #pragma unroll
    for (int r = 0; r < 16; ++r) { acc[r] = 0.f; z16[r] = 0.f; }
    float lsum = 0.f;

    const int vbeg = wave * 512;
    const __bf16* kbase = kTb + (size_t)swl * NC;
    const __bf16* vbase = Vb + (size_t)wl * NW;

#define KLD0(V0) (*(const bf16x8*)(kbase + (size_t)(V0) * NC + hi*8))
#define KLD1(V0) (*(const bf16x8*)(kbase + (size_t)(V0) * NC + 16 + hi*8))
#define VLD0(V0) (*(const bf16x8*)(vbase + (V0) + hi*8))
#define VLD1(V0) (*(const bf16x8*)(vbase + (V0) + 16 + hi*8))

    bf16x8 k0r = KLD0(vbeg), k1r = KLD1(vbeg);
    f32x16 s_cur = __builtin_amdgcn_mfma_f32_32x32x16_bf16(k0r, qf0, z16, 0, 0, 0);
    s_cur = __builtin_amdgcn_mfma_f32_32x32x16_bf16(k1r, qf1, s_cur, 0, 0, 0);
    k0r = KLD0(vbeg + 32); k1r = KLD1(vbeg + 32);
    bf16x8 v0r = VLD0(vbeg), v1r = VLD1(vbeg);

    #pragma unroll
    for (int it = 0; it < 16; ++it) {
        f32x16 s_next;
        if (it < 15) {
            s_next = __builtin_amdgcn_mfma_f32_32x32x16_bf16(k0r, qf0, z16, 0, 0, 0);
            s_next = __builtin_amdgcn_mfma_f32_32x32x16_bf16(k1r, qf1, s_next, 0, 0, 0);
        }
        if (it < 14) {
            const int vn = vbeg + (it + 2) * 32;
            k0r = KLD0(vn); k1r = KLD1(vn);
        }

        float p[16];
        #pragma unroll
        for (int r = 0; r < 16; ++r) p[r] = __builtin_amdgcn_exp2f(s_cur[r]);
        float ts[8];
        #pragma unroll
        for (int r = 0; r < 8; ++r) ts[r] = p[r] + p[r+8];
        #pragma unroll
        for (int r = 0; r < 4; ++r) ts[r] += ts[r+4];
        lsum += (ts[0] + ts[1]) + (ts[2] + ts[3]);

        union { unsigned int u[4]; bf16x8 v; } pfa, pfb;
        #pragma unroll
        for (int i = 0; i < 4; ++i) pfa.u[i] = pk2(p[2*i],     p[2*i + 1]);
        #pragma unroll
        for (int i = 0; i < 4; ++i) pfb.u[i] = pk2(p[8 + 2*i], p[8 + 2*i + 1]);

        acc = __builtin_amdgcn_mfma_f32_32x32x16_bf16(v0r, pfa.v, acc, 0, 0, 0);
        acc = __builtin_amdgcn_mfma_f32_32x32x16_bf16(v1r, pfb.v, acc, 0, 0, 0);

        if (it < 15) {
            const int vn = vbeg + (it + 1) * 32;
            v0r = VLD0(vn); v1r = VLD1(vn);
            s_cur = s_next;
        }
    }
#undef KLD0
#undef KLD1
#undef VLD0
#undef VLD1
    lsum += __shfl_xor(lsum, 32);

    __shared__ float sl[4][32];
    __shared__ float sO[4][32][33];
    __shared__ float Of[32][33];

    if (hi == 0) sl[wave][wl] = lsum;
    #pragma unroll
    for (int r = 0; r < 16; ++r) {
        const int c = (r & 3) + 8*(r >> 2) + 4*hi;
        sO[wave][c][wl] = acc[r];
    }
    __syncthreads();

    {
        const int w  = threadIdx.x & 31;
        const int cg = threadIdx.x >> 5;
        const float L = (sl[0][w] + sl[1][w]) + (sl[2][w] + sl[3][w]);
        const float rL = 1.0f / L;
        #pragma unroll
        for (int cc = 0; cc < 4; ++cc) {
            const int c = cg * 4 + cc;
            const float o = ((sO[0][c][w] + sO[1][c][w]) +
                             (sO[2][c][w] + sO[3][c][w]));
            Of[c][w] = o * rL;
        }
    }
    __syncthreads();

    const float* xb = x   + (size_t)b * NC * NH * NW + w0;
    float*       ob = out + (size_t)b * NC * NH * NW + w0;
    const int chunk = threadIdx.x & 7;
    #pragma unroll
    for (int it = 0; it < 32; ++it) {
        const int row = it*32 + (threadIdx.x >> 3);
        const int c = row >> 5, h = row & 31;
        const size_t off = ((size_t)c * NH + h) * NW + chunk*4;
        const f32x4 xv = *(const f32x4*)(xb + off);
        f32x4 ov;
        ov[0] = Of[c][chunk*4 + 0] + xv[0];
        ov[1] = Of[c][chunk*4 + 1] + xv[1];
        ov[2] = Of[c][chunk*4 + 2] + xv[2];
        ov[3] = Of[c][chunk*4 + 3] + xv[3];
        __builtin_nontemporal_store(ov, (f32x4*)(ob + off));
    }
}

extern "C" void kernel_launch(void* const* d_in, const int* in_sizes, int n_in,
                              void* d_out, int out_size, void* d_ws, size_t ws_size,
                              hipStream_t stream)
{
    const float* x  = (const float*)d_in[0];
    const float* wq = (const float*)d_in[1];
    const float* bq = (const float*)d_in[2];
    const float* wk = (const float*)d_in[3];
    const float* bk = (const float*)d_in[4];
    const float* wv = (const float*)d_in[5];
    const float* bv = (const float*)d_in[6];
    float* out = (float*)d_out;

    // ws layout (bf16): qT [B][W][32] @0, kT @2MB, V [B][32][W] @4MB, wb @6MB
    char* ws = (char*)d_ws;
    __bf16* qT = (__bf16*)(ws);
    __bf16* kT = (__bf16*)(ws + (2u << 20));
    __bf16* V  = (__bf16*)(ws + (4u << 20));
    __bf16* wb = (__bf16*)(ws + (6u << 20));

    hipLaunchKernelGGL(wprep_kernel, dim3(96), dim3(256), 0, stream, wq, wk, wv, wb);
    hipLaunchKernelGGL(proj_kernel, dim3(NB * 64), dim3(384), 0, stream,
                       x, wb, bq, bk, bv, qT, kT, V);
    hipLaunchKernelGGL(attn_kernel, dim3(NB * 64), dim3(256), 0, stream,
                       x, qT, kT, V, out);
}

// Round 19
// 96.911 us; speedup vs baseline: 1.0065x; 1.0065x over previous
//
#include <hip/hip_runtime.h>
#include <hip/hip_bf16.h>

typedef __bf16 bf16x8 __attribute__((ext_vector_type(8)));
typedef float  f32x4  __attribute__((ext_vector_type(4)));
typedef float  f32x16 __attribute__((ext_vector_type(16)));

#define NB 16
#define NC 32
#define NH 32
#define NW 2048
#define NK (NC*NH)   // 1024
#define LOG2E 1.4426950408889634f
#define KP 40        // LDS k-pitch (bf16): 80 B rows

static __device__ __forceinline__ unsigned int pk2(float a, float b) {
    union { __bf16 h[2]; unsigned int u; } z;
    z.h[0] = (__bf16)a; z.h[1] = (__bf16)b;
    return z.u;
}

// ---------------------------------------------------------------------------
// Kernel 0: weights -> bf16. wb layout [3][32][1024]; wq scaled by log2e.
// ---------------------------------------------------------------------------
__global__ __launch_bounds__(256) void wprep_kernel(
    const float* __restrict__ wq, const float* __restrict__ wk,
    const float* __restrict__ wv, __bf16* __restrict__ wb)
{
    const int i = blockIdx.x * 256 + threadIdx.x;        // 24576 float4 units
    const float* srcs[3] = { wq, wk, wv };
    float4 v = *(const float4*)(srcs[i >> 13] + (size_t)(i & 8191) * 4);
    const float sc = (i >> 13) == 0 ? LOG2E : 1.0f;
    union { __bf16 h[4]; unsigned long long u; } z;
    z.h[0] = (__bf16)(v.x * sc); z.h[1] = (__bf16)(v.y * sc);
    z.h[2] = (__bf16)(v.z * sc); z.h[3] = (__bf16)(v.w * sc);
    *(unsigned long long*)(wb + (size_t)i * 4) = z.u;
}

// ---------------------------------------------------------------------------
// Kernel 1 (v8): QKV projection = v4 skeleton + REGISTER-TRANSPOSE staging.
// Stager thread loads float2 from rows 2kp,2kp+1 (coalesced 128B/row,
// 4 rows per instruction), pk2-packs the k-pairs in REGISTERS, and issues
// just 2 ds_write_b32 per step at 4-way conflict (16 banks/instr) --
// replacing v4's 16 ds_write_b16 at 8-way (8 banks/instr): ~10x less
// LDS-write-pipe time. Tile [2][32w][40k] bf16 (dword [32][20] view),
// frag reads / MFMAs / epilogue identical to v4 (R14, best=93.9).
// 6 waves (384 thr), waves 0..3 stage+compute, 5 KB LDS, grid 1024.
// ---------------------------------------------------------------------------
__global__ __launch_bounds__(384) void proj_kernel(
    const float* __restrict__ x, const __bf16* __restrict__ wb,
    const float* __restrict__ bq, const float* __restrict__ bk,
    const float* __restrict__ bv,
    __bf16* __restrict__ qT, __bf16* __restrict__ kT, __bf16* __restrict__ V)
{
    const int b    = blockIdx.x >> 6;
    const int wt   = blockIdx.x & 63;
    const int nt   = threadIdx.x >> 6;       // wave = output ntile 0..5
    const int lane = threadIdx.x & 63;
    const int g    = lane >> 4;
    const int lr   = lane & 15;
    const int w0   = wt * 32;

    __shared__ __bf16 tile[2][32][KP];       // 5 KB total

    const float* xb = x + (size_t)b * NK * NW;
    const bool stager = (threadIdx.x < 256);

    // stager map: kp = k-pair 0..15, swq2 = w-pair 0..15 -> w = 2*swq2
    const int kp   = threadIdx.x >> 4;       // 0..15
    const int swq2 = threadIdx.x & 15;       // 0..15
    const float* xs = xb + w0 + 2 * swq2;

    const __bf16* wrow = wb + (size_t)(nt >> 1) * 32768
                            + (size_t)((nt & 1) * 16 + lr) * NK;

    f32x4 acc0 = {0.f,0.f,0.f,0.f}, acc1 = {0.f,0.f,0.f,0.f};
    float2 ra, rc;                           // staging regs (static names)

#define SLOAD(S)                                                              \
    { ra = *(const float2*)(xs + (size_t)((S)*32 + 2*kp)     * NW);           \
      rc = *(const float2*)(xs + (size_t)((S)*32 + 2*kp + 1) * NW); }

#define SWRITE(BUF)                                                           \
    { *(unsigned int*)&tile[BUF][2*swq2    ][2*kp] = pk2(ra.x, rc.x);         \
      *(unsigned int*)&tile[BUF][2*swq2 + 1][2*kp] = pk2(ra.y, rc.y); }

    // ---- prologue: stage step 0 ----
    if (stager) { SLOAD(0); SWRITE(0); }
    bf16x8 Bcur = *(const bf16x8*)(wrow + g*8);
    __syncthreads();

    #pragma unroll
    for (int s = 0; s < 32; ++s) {
        const int cur = s & 1;
        // issue next step's loads first (hidden under this step's compute)
        if (s < 31 && stager) { SLOAD(s + 1); }
        bf16x8 Bnext;
        if (s < 31) Bnext = *(const bf16x8*)(wrow + (s+1)*32 + g*8);

        // consume: A-frags via ds_read_b128, 2 MFMAs
        const bf16x8 af0 = *(const bf16x8*)&tile[cur][lr][g*8];
        const bf16x8 af1 = *(const bf16x8*)&tile[cur][16 + lr][g*8];
        acc0 = __builtin_amdgcn_mfma_f32_16x16x32_bf16(af0, Bcur, acc0, 0, 0, 0);
        acc1 = __builtin_amdgcn_mfma_f32_16x16x32_bf16(af1, Bcur, acc1, 0, 0, 0);

        // stage next step into the other buffer (2 conflict-light b32 writes)
        if (s < 31 && stager) { SWRITE(cur ^ 1); }
        Bcur = Bnext;
        __syncthreads();
    }
#undef SLOAD
#undef SWRITE

    // ---- epilogue: bias + store this wave's 16 channels x 32 w ----
    const int pid = nt >> 1;                 // 0=q,1=k,2=v
    const int o   = (nt & 1) * 16 + lr;
    const float* biases[3] = { bq, bk, bv };
    float bb = biases[pid][o];
    if (pid == 0) bb *= LOG2E;

    if (pid < 2) {
        __bf16* dst = (pid ? kT : qT) + (size_t)b * NW * NC;
        #pragma unroll
        for (int r = 0; r < 4; ++r) {
            dst[(size_t)(w0 +      g*4 + r) * NC + o] = (__bf16)(acc0[r] + bb);
            dst[(size_t)(w0 + 16 + g*4 + r) * NC + o] = (__bf16)(acc1[r] + bb);
        }
    } else {
        __bf16* dst = V + ((size_t)b * NC + o) * NW + w0;
        union { __bf16 h[4]; unsigned long long u; } z0, z1;
        #pragma unroll
        for (int r = 0; r < 4; ++r) {
            z0.h[r] = (__bf16)(acc0[r] + bb);
            z1.h[r] = (__bf16)(acc1[r] + bb);
        }
        *(unsigned long long*)(dst +      g*4) = z0.u;
        *(unsigned long long*)(dst + 16 + g*4) = z1.u;
    }
}

// ---------------------------------------------------------------------------
// Kernel 2: flash attention (R10/R14, unchanged/verified): fixed-max softmax,
// sigma-permuted K rows (lane-local PV fragments), software-pipelined loop,
// exp2 via __builtin_amdgcn_exp2f, NT out stores.
// ---------------------------------------------------------------------------
__global__ __launch_bounds__(256) void attn_kernel(
    const float* __restrict__ x,
    const __bf16* __restrict__ qT, const __bf16* __restrict__ kT,
    const __bf16* __restrict__ V,
    float* __restrict__ out)
{
    const int b    = blockIdx.x >> 6;
    const int wt   = blockIdx.x & 63;
    const int w0   = wt * 32;
    const int wave = threadIdx.x >> 6;        // KV slice 0..3
    const int lane = threadIdx.x & 63;
    const int wl = lane & 31, hi = lane >> 5;
    const int swl = (wl & 0x13) | ((wl & 4) << 1) | ((wl & 8) >> 1);

    const __bf16* qTb = qT + (size_t)b * NW * NC;
    const __bf16* kTb = kT + (size_t)b * NW * NC;
    const __bf16* Vb  = V  + (size_t)b * NC * NW;

    const __bf16* qrow = qTb + (size_t)(w0 + wl) * NC;
    const bf16x8 qf0 = *(const bf16x8*)(qrow + hi*8);
    const bf16x8 qf1 = *(const bf16x8*)(qrow + 16 + hi*8);

    f32x16 acc, z16;
    #pragma unroll
    for (int r = 0; r < 16; ++r) { acc[r] = 0.f; z16[r] = 0.f; }
    float lsum = 0.f;

    const int vbeg = wave * 512;
    const __bf16* kbase = kTb + (size_t)swl * NC;
    const __bf16* vbase = Vb + (size_t)wl * NW;

#define KLD0(V0) (*(const bf16x8*)(kbase + (size_t)(V0) * NC + hi*8))
#define KLD1(V0) (*(const bf16x8*)(kbase + (size_t)(V0) * NC + 16 + hi*8))
#define VLD0(V0) (*(const bf16x8*)(vbase + (V0) + hi*8))
#define VLD1(V0) (*(const bf16x8*)(vbase + (V0) + 16 + hi*8))

    bf16x8 k0r = KLD0(vbeg), k1r = KLD1(vbeg);
    f32x16 s_cur = __builtin_amdgcn_mfma_f32_32x32x16_bf16(k0r, qf0, z16, 0, 0, 0);
    s_cur = __builtin_amdgcn_mfma_f32_32x32x16_bf16(k1r, qf1, s_cur, 0, 0, 0);
    k0r = KLD0(vbeg + 32); k1r = KLD1(vbeg + 32);
    bf16x8 v0r = VLD0(vbeg), v1r = VLD1(vbeg);

    #pragma unroll
    for (int it = 0; it < 16; ++it) {
        f32x16 s_next;
        if (it < 15) {
            s_next = __builtin_amdgcn_mfma_f32_32x32x16_bf16(k0r, qf0, z16, 0, 0, 0);
            s_next = __builtin_amdgcn_mfma_f32_32x32x16_bf16(k1r, qf1, s_next, 0, 0, 0);
        }
        if (it < 14) {
            const int vn = vbeg + (it + 2) * 32;
            k0r = KLD0(vn); k1r = KLD1(vn);
        }

        float p[16];
        #pragma unroll
        for (int r = 0; r < 16; ++r) p[r] = __builtin_amdgcn_exp2f(s_cur[r]);
        float ts[8];
        #pragma unroll
        for (int r = 0; r < 8; ++r) ts[r] = p[r] + p[r+8];
        #pragma unroll
        for (int r = 0; r < 4; ++r) ts[r] += ts[r+4];
        lsum += (ts[0] + ts[1]) + (ts[2] + ts[3]);

        union { unsigned int u[4]; bf16x8 v; } pfa, pfb;
        #pragma unroll
        for (int i = 0; i < 4; ++i) pfa.u[i] = pk2(p[2*i],     p[2*i + 1]);
        #pragma unroll
        for (int i = 0; i < 4; ++i) pfb.u[i] = pk2(p[8 + 2*i], p[8 + 2*i + 1]);

        acc = __builtin_amdgcn_mfma_f32_32x32x16_bf16(v0r, pfa.v, acc, 0, 0, 0);
        acc = __builtin_amdgcn_mfma_f32_32x32x16_bf16(v1r, pfb.v, acc, 0, 0, 0);

        if (it < 15) {
            const int vn = vbeg + (it + 1) * 32;
            v0r = VLD0(vn); v1r = VLD1(vn);
            s_cur = s_next;
        }
    }
#undef KLD0
#undef KLD1
#undef VLD0
#undef VLD1
    lsum += __shfl_xor(lsum, 32);

    __shared__ float sl[4][32];
    __shared__ float sO[4][32][33];
    __shared__ float Of[32][33];

    if (hi == 0) sl[wave][wl] = lsum;
    #pragma unroll
    for (int r = 0; r < 16; ++r) {
        const int c = (r & 3) + 8*(r >> 2) + 4*hi;
        sO[wave][c][wl] = acc[r];
    }
    __syncthreads();

    {
        const int w  = threadIdx.x & 31;
        const int cg = threadIdx.x >> 5;
        const float L = (sl[0][w] + sl[1][w]) + (sl[2][w] + sl[3][w]);
        const float rL = 1.0f / L;
        #pragma unroll
        for (int cc = 0; cc < 4; ++cc) {
            const int c = cg * 4 + cc;
            const float o = ((sO[0][c][w] + sO[1][c][w]) +
                             (sO[2][c][w] + sO[3][c][w]));
            Of[c][w] = o * rL;
        }
    }
    __syncthreads();

    const float* xb = x   + (size_t)b * NC * NH * NW + w0;
    float*       ob = out + (size_t)b * NC * NH * NW + w0;
    const int chunk = threadIdx.x & 7;
    #pragma unroll
    for (int it = 0; it < 32; ++it) {
        const int row = it*32 + (threadIdx.x >> 3);
        const int c = row >> 5, h = row & 31;
        const size_t off = ((size_t)c * NH + h) * NW + chunk*4;
        const f32x4 xv = *(const f32x4*)(xb + off);
        f32x4 ov;
        ov[0] = Of[c][chunk*4 + 0] + xv[0];
        ov[1] = Of[c][chunk*4 + 1] + xv[1];
        ov[2] = Of[c][chunk*4 + 2] + xv[2];
        ov[3] = Of[c][chunk*4 + 3] + xv[3];
        __builtin_nontemporal_store(ov, (f32x4*)(ob + off));
    }
}

extern "C" void kernel_launch(void* const* d_in, const int* in_sizes, int n_in,
                              void* d_out, int out_size, void* d_ws, size_t ws_size,
                              hipStream_t stream)
{
    const float* x  = (const float*)d_in[0];
    const float* wq = (const float*)d_in[1];
    const float* bq = (const float*)d_in[2];
    const float* wk = (const float*)d_in[3];
    const float* bk = (const float*)d_in[4];
    const float* wv = (const float*)d_in[5];
    const float* bv = (const float*)d_in[6];
    float* out = (float*)d_out;

    // ws layout (bf16): qT [B][W][32] @0, kT @2MB, V [B][32][W] @4MB, wb @6MB
    char* ws = (char*)d_ws;
    __bf16* qT = (__bf16*)(ws);
    __bf16* kT = (__bf16*)(ws + (2u << 20));
    __bf16* V  = (__bf16*)(ws + (4u << 20));
    __bf16* wb = (__bf16*)(ws + (6u << 20));

    hipLaunchKernelGGL(wprep_kernel, dim3(96), dim3(256), 0, stream, wq, wk, wv, wb);
    hipLaunchKernelGGL(proj_kernel, dim3(NB * 64), dim3(384), 0, stream,
                       x, wb, bq, bk, bv, qT, kT, V);
    hipLaunchKernelGGL(attn_kernel, dim3(NB * 64), dim3(256), 0, stream,
                       x, qT, kT, V, out);
}